// Round 15
// baseline (1073.108 us; speedup 1.0000x reference)
//
#include <hip/hip_runtime.h>
#include <hip/hip_bf16.h>

#define BATCH 256
#define SEQ   250
#define HID   512
#define INDIM 5

#define NBLK  128
#define NCH   16   // independent batch chains (2 per block)
#define MB    16   // batch rows per chain
#define HB    32   // hidden cols per block per gate -> 16 members per chain
#define NMEM  16   // members per chain (HID/HB)

// member-major h buffers: slot (2) | chain (16) | member (16) | 1KB
//   member block global: 16 rows (batch) x 32 cols (hidden) bf16 = 1KB
// LDS member block: 16 rows x 36 ushorts (72B: 64B data + 8B pad)
#define LROWU 36
#define LMEMU 576
#define SLOT_BYTES (BATCH * HID * 2)   // 256KB per slot

typedef __attribute__((ext_vector_type(8))) short short8;
typedef __attribute__((ext_vector_type(4))) float f32x4;
typedef __attribute__((ext_vector_type(4))) unsigned int u32x4;

__device__ __forceinline__ float sigmoidf_fast(float x) {
  return 1.0f / (1.0f + __expf(-x));
}
__device__ __forceinline__ float tanhf_fast(float x) {
  return 2.0f / (1.0f + __expf(-2.0f * x)) - 1.0f;
}
__device__ __forceinline__ unsigned short f2bf_rne(float x) {
  union { float f; unsigned u; } v; v.f = x;
  unsigned r = v.u + 0x7fffu + ((v.u >> 16) & 1u);
  return (unsigned short)(r >> 16);
}
__device__ __forceinline__ float bf2f(unsigned short h) {
  union { unsigned u; float f; } v; v.u = ((unsigned)h) << 16;
  return v.f;
}

// R15: TWO interleaved chains per block (128 blocks = member 0..15 x pair
// 0..7; chains 2p, 2p+1). Phase A computes chain A's step while chain B's
// just-published flags propagate, and vice versa: the publish->detect MALL
// leg (the R14 floor) is hidden under the other chain's compute. W_hh
// fragments shared (identical weights). h_lds/g_lds reused across phases
// (B's staging writes follow B-sync#1 which follows all waves' A-act).
// Protocol per chain unchanged from R14: fused L2+MALL dual-probe poll,
// dual publish, per-(member,wave) flags. bid = m*8+p -> bid%8 = p keeps
// each pair on one XCD under round-robin (verdict check covers fallback).
__global__ __launch_bounds__(256, 1) void lstm_persist(
    const float* __restrict__ strokes, const float* __restrict__ W_ih,
    const float* __restrict__ W_hh, const float* __restrict__ b_ih,
    const float* __restrict__ b_hh, const float* __restrict__ W_out,
    const float* __restrict__ b_out, float* __restrict__ out,
    unsigned short* __restrict__ hbuf,   // 2 slots * 256KB, member-major
    int* __restrict__ flagsML,           // 16*16*16 ints, MALL copy (poison<0)
    int* __restrict__ flagsL2,           // 16*16*16 ints, L2 copy   (poison<0)
    int* __restrict__ xcd_ids,           // 128 ints (poison < 0)
    int* __restrict__ vflag)             // 8*16 ints verdicts (poison < 0)
{
  const int tid  = threadIdx.x;
  const int bid  = blockIdx.x;
  const int p    = bid & 7;      // chain pair 0..7 (chains 2p, 2p+1)
  const int m    = bid >> 3;     // member 0..15
  const int wv   = tid >> 6;     // wave id = gate type 0..3 (i,f,g,o)
  const int lane = tid & 63;
  const int n16  = lane & 15;
  const int q    = lane >> 4;

  __shared__ unsigned short h_lds[NMEM * LMEMU];  // 18KB, reused both phases
  __shared__ float g_lds[4][MB][33];              // gates, reused both phases
  __shared__ float wih_lds[4][HB][INDIM];
  __shared__ float bias_lds[4][HB];
  __shared__ int fast_s;

  // ---- publish my XCC id (device scope)
  unsigned xcc;
  asm volatile("s_getreg_b32 %0, hwreg(HW_REG_XCC_ID)" : "=s"(xcc));
  xcc &= 0xfu;
  if (tid == 0) {
    __hip_atomic_store(&xcd_ids[bid], (int)xcc, __ATOMIC_RELAXED,
                       __HIP_MEMORY_SCOPE_AGENT);
  }
  // ---- leader (m==0, i.e. bid<8) computes pair verdict, BOUNDED poll
  if (bid < 8 && wv == 0) {
    int other = (int)xcc;
    if (lane < NMEM) {
      const int* xp = &xcd_ids[lane * 8 + p];
      other = -1;
      for (int it = 0; it < 16384 && other < 0; ++it) {
        other = __hip_atomic_load(xp, __ATOMIC_RELAXED, __HIP_MEMORY_SCOPE_AGENT);
      }
    }
    unsigned long long ok = __ballot(other == (int)xcc);
    if (lane == 0) {
      __hip_atomic_store(&vflag[p * 16], (ok == ~0ull) ? 2 : 1,
                         __ATOMIC_RELAXED, __HIP_MEMORY_SCOPE_AGENT);
    }
  }
  if (tid == 0) {   // wait leader (co-resident, bounded work -> terminates)
    int v;
    do {
      v = __hip_atomic_load(&vflag[p * 16], __ATOMIC_RELAXED,
                            __HIP_MEMORY_SCOPE_AGENT);
    } while (v <= 0);
    fast_s = (v == 2) ? 1 : 0;
  }

  // ---- preload W_ih slice + combined biases into LDS (HB=32 per gate)
  if (tid < 128) {
    int g = tid >> 5, j = tid & 31;
    int r = g * HID + m * HB + j;
    #pragma unroll
    for (int i = 0; i < INDIM; ++i) wih_lds[g][j][i] = W_ih[r * INDIM + i];
    bias_lds[g][j] = b_ih[r] + b_hh[r];
  }

  // ---- preload W_hh as bf16 MFMA B-fragments (shared by both chains),
  // 2 N-tiles per wave, rotated: wfrag[i][nt] <-> kb=(wv*4+i)&15
  short8 wfrag[16][2];
  {
    #pragma unroll
    for (int i = 0; i < 16; ++i) {
      const int kb = (wv * 4 + i) & 15;
      #pragma unroll
      for (int nt = 0; nt < 2; ++nt) {
        const float* pw = W_hh
            + (size_t)(wv * HID + m * HB + nt * 16 + n16) * HID
            + kb * 32 + q * 8;
        short8 f;
        #pragma unroll
        for (int j = 0; j < 8; ++j) f[j] = (short)f2bf_rne(pw[j]);
        wfrag[i][nt] = f;
      }
    }
  }
  __syncthreads();
  const bool fast = fast_s != 0;

  // activation-phase mapping: thread -> (batch row am, hidden pair ajp)
  const int am  = tid >> 4;           // 0..15
  const int ajp = (tid & 15) * 2;     // 0,2,..,30
  const int j0m = wv * 4;             // this wave's first member
  float cst[2][2] = {{0.f, 0.f}, {0.f, 0.f}};   // c-state per chain, 2 cells

  // ---- one chain-step phase (inlined twice per iteration with ci literal)
  auto phase = [&](int ci, int t) {
    const int chain = p * 2 + ci;
    const int ab    = chain * MB + am;
    char* hslotprev = reinterpret_cast<char*>(hbuf)
                    + (((t & 1) ^ 1) ? SLOT_BYTES : 0);
    char* hslotcur  = reinterpret_cast<char*>(hbuf)
                    + ((t & 1) ? SLOT_BYTES : 0);

    const float* sp = strokes + ((size_t)ab * SEQ + t) * INDIM;
    float s0 = sp[0], s1 = sp[1], s2 = sp[2], s3 = sp[3], s4 = sp[4];

    f32x4 acc[2][2] = {};   // [ntile][parity]
    if (t > 0) {
      // ---- poll 4 members x 4 wave-flags (lanes 0..15): fused dual-probe
      if (lane < 16) {
        const int fi = (chain * 16 + (j0m + (lane >> 2))) * 16 + (lane & 3) * 4;
        const int* fpL = &flagsL2[fi];
        const int* fpM = &flagsML[fi];
        if (fast) {
          int v;
          do {
            int v1, v2;
            asm volatile("global_load_dword %0, %2, off sc0\n\t"
                         "global_load_dword %1, %3, off sc0 sc1\n\t"
                         "s_waitcnt vmcnt(0)"
                         : "=v"(v1), "=v"(v2)
                         : "v"(fpL), "v"(fpM)
                         : "memory");
            v = v1 > v2 ? v1 : v2;
          } while (v < t);
        } else {
          while (__hip_atomic_load(fpM, __ATOMIC_RELAXED,
                                   __HIP_MEMORY_SCOPE_AGENT) < t) { }
        }
      }
      // ---- stage this wave's 4 members (4 x 1KB) into LDS
      const char* base = hslotprev + chain * 16384 + j0m * 1024;
      u32x4 tmp[4];
      if (fast) {
        #pragma unroll
        for (int i = 0; i < 4; ++i)
          asm volatile("global_load_dwordx4 %0, %1, off sc0"
                       : "=v"(tmp[i])
                       : "v"(base + (size_t)(i * 64 + lane) * 16) : "memory");
      } else {
        #pragma unroll
        for (int i = 0; i < 4; ++i)
          asm volatile("global_load_dwordx4 %0, %1, off sc0 sc1"
                       : "=v"(tmp[i])
                       : "v"(base + (size_t)(i * 64 + lane) * 16) : "memory");
      }
      asm volatile("s_waitcnt vmcnt(0)" ::: "memory");
      #pragma unroll
      for (int i = 0; i < 4; ++i) {
        const int idx = i * 64 + lane;
        const int mm  = j0m + (idx >> 6);
        const int c   = idx & 63;
        *reinterpret_cast<u32x4*>(
            &h_lds[mm * LMEMU + (c >> 2) * LROWU + (c & 3) * 8]) = tmp[i];
      }

      // ---- early MFMA: the 4 kb (== members) this wave itself staged
      #pragma unroll
      for (int i = 0; i < 4; ++i) {
        const int kb = wv * 4 + i;
        const short8 a = *reinterpret_cast<const short8*>(
            &h_lds[kb * LMEMU + n16 * LROWU + q * 8]);
        #pragma unroll
        for (int nt = 0; nt < 2; ++nt)
          acc[nt][i & 1] = __builtin_amdgcn_mfma_f32_16x16x32_bf16(
              a, wfrag[i][nt], acc[nt][i & 1], 0, 0, 0);
      }
      __syncthreads();   // sync#1: all waves' staging visible
      #pragma unroll
      for (int i = 4; i < 16; ++i) {
        const int kb = (wv * 4 + i) & 15;
        const short8 a = *reinterpret_cast<const short8*>(
            &h_lds[kb * LMEMU + n16 * LROWU + q * 8]);
        #pragma unroll
        for (int nt = 0; nt < 2; ++nt)
          acc[nt][i & 1] = __builtin_amdgcn_mfma_f32_16x16x32_bf16(
              a, wfrag[i][nt], acc[nt][i & 1], 0, 0, 0);
      }
    } else {
      __syncthreads();   // keep barrier count uniform at t==0
    }

    // C-layout per N-tile: col = nt*16 + (lane&15), row = q*4 + reg
    #pragma unroll
    for (int nt = 0; nt < 2; ++nt) {
      #pragma unroll
      for (int r = 0; r < 4; ++r) {
        g_lds[wv][q * 4 + r][nt * 16 + n16] = acc[nt][0][r] + acc[nt][1][r];
      }
    }
    __syncthreads();   // sync#2: gates visible to all waves

    // ---- act: 2 cells per thread (batch am, hidden ajp, ajp+1)
    float hv[2];
    #pragma unroll
    for (int e = 0; e < 2; ++e) {
      const int j = ajp + e;
      float pre[4];
      #pragma unroll
      for (int g = 0; g < 4; ++g) {
        pre[g] = bias_lds[g][j] + g_lds[g][am][j]
               + s0 * wih_lds[g][j][0] + s1 * wih_lds[g][j][1]
               + s2 * wih_lds[g][j][2] + s3 * wih_lds[g][j][3]
               + s4 * wih_lds[g][j][4];
      }
      float ig = sigmoidf_fast(pre[0]);
      float fg = sigmoidf_fast(pre[1]);
      float gg = tanhf_fast(pre[2]);
      float og = sigmoidf_fast(pre[3]);
      float& c = cst[ci][e];
      c = fg * c + ig * gg;
      hv[e] = og * tanhf_fast(c);
    }
    // h store: one dword (2 bf16) into member m's 1KB block of this chain
    unsigned pack = (unsigned)f2bf_rne(hv[0]) | ((unsigned)f2bf_rne(hv[1]) << 16);
    unsigned* hp = reinterpret_cast<unsigned*>(
        hslotcur + chain * 16384 + m * 1024 + am * 64 + ajp * 2);
    if (fast) {
      asm volatile("global_store_dword %0, %1, off sc0"
                   :: "v"(hp), "v"(pack) : "memory");
    } else {
      __hip_atomic_store(hp, pack, __ATOMIC_RELAXED, __HIP_MEMORY_SCOPE_AGENT);
    }

    // ---- per-wave publish: drain OWN wave's h stores, then flag
    asm volatile("s_waitcnt vmcnt(0)" ::: "memory");
    const int gen = t + 1;
    if (lane == 0) {
      const int fi = (chain * 16 + m) * 16 + wv * 4;
      if (fast) {
        asm volatile("global_store_dword %0, %1, off sc0"
                     :: "v"(&flagsL2[fi]), "v"(gen) : "memory");
      }
      __hip_atomic_store(&flagsML[fi], gen, __ATOMIC_RELAXED,
                         __HIP_MEMORY_SCOPE_AGENT);   // MALL copy
    }
  };

  for (int t = 0; t < SEQ; ++t) {
    phase(0, t);   // chain 2p   -- its poll slack = chain B's phase time
    phase(1, t);   // chain 2p+1 -- its poll slack = chain A's phase time
  }

  // ---- final projection: member m==0 blocks (bid<8) handle both chains.
  if (m == 0) {
    #pragma unroll 1
    for (int ci = 0; ci < 2; ++ci) {
      const int chain = p * 2 + ci;
      if (lane < 16) {
        const int fi = (chain * 16 + (j0m + (lane >> 2))) * 16 + (lane & 3) * 4;
        const int* fpL = &flagsL2[fi];
        const int* fpM = &flagsML[fi];
        if (fast) {
          int v;
          do {
            int v1, v2;
            asm volatile("global_load_dword %0, %2, off sc0\n\t"
                         "global_load_dword %1, %3, off sc0 sc1\n\t"
                         "s_waitcnt vmcnt(0)"
                         : "=v"(v1), "=v"(v2)
                         : "v"(fpL), "v"(fpM)
                         : "memory");
            v = v1 > v2 ? v1 : v2;
          } while (v < SEQ);
        } else {
          while (__hip_atomic_load(fpM, __ATOMIC_RELAXED,
                                   __HIP_MEMORY_SCOPE_AGENT) < SEQ) { }
        }
      }
      const char* base = reinterpret_cast<const char*>(hbuf)
                       + ((SEQ - 1) & 1) * SLOT_BYTES + chain * 16384
                       + j0m * 1024;
      u32x4 tmp[4];
      if (fast) {
        #pragma unroll
        for (int i = 0; i < 4; ++i)
          asm volatile("global_load_dwordx4 %0, %1, off sc0"
                       : "=v"(tmp[i])
                       : "v"(base + (size_t)(i * 64 + lane) * 16) : "memory");
      } else {
        #pragma unroll
        for (int i = 0; i < 4; ++i)
          asm volatile("global_load_dwordx4 %0, %1, off sc0 sc1"
                       : "=v"(tmp[i])
                       : "v"(base + (size_t)(i * 64 + lane) * 16) : "memory");
      }
      asm volatile("s_waitcnt vmcnt(0)" ::: "memory");
      #pragma unroll
      for (int i = 0; i < 4; ++i) {
        const int idx = i * 64 + lane;
        const int mm  = j0m + (idx >> 6);
        const int c   = idx & 63;
        *reinterpret_cast<u32x4*>(
            &h_lds[mm * LMEMU + (c >> 2) * LROWU + (c & 3) * 8]) = tmp[i];
      }
      __syncthreads();
      if (tid < MB) {
        const int b = chain * MB + tid;
        float s = 0.f;
        for (int k = 0; k < HID; ++k) {
          s += bf2f(h_lds[(k >> 5) * LMEMU + tid * LROWU + (k & 31)]) * W_out[k];
        }
        float raw = s + b_out[0];
        float lr = raw > 0.f ? raw : 0.1f * raw;
        out[b] = 1.0f / (1.0f + __expf(-lr));
      }
      __syncthreads();   // h_lds reused by second chain
    }
  }
}

extern "C" void kernel_launch(void* const* d_in, const int* in_sizes, int n_in,
                              void* d_out, int out_size, void* d_ws, size_t ws_size,
                              hipStream_t stream) {
  const float* strokes = (const float*)d_in[0];
  const float* W_ih    = (const float*)d_in[1];
  const float* W_hh    = (const float*)d_in[2];
  const float* b_ih    = (const float*)d_in[3];
  const float* b_hh    = (const float*)d_in[4];
  const float* W_out   = (const float*)d_in[5];
  const float* b_out   = (const float*)d_in[6];
  float* out = (float*)d_out;

  char* ws = (char*)d_ws;
  unsigned short* hbuf = (unsigned short*)ws;                 // 512 KB (2 slots)
  size_t off = (size_t)2 * SLOT_BYTES;
  int* flagsML = (int*)(ws + off);  off += 16384;             // 16 KB
  int* flagsL2 = (int*)(ws + off);  off += 16384;             // 16 KB
  int* xcd_ids = (int*)(ws + off);  off += 2048;              // 2 KB
  int* vflag   = (int*)(ws + off);                            // 512 B

  lstm_persist<<<NBLK, 256, 0, stream>>>(strokes, W_ih, W_hh, b_ih, b_hh,
                                         W_out, b_out, out, hbuf,
                                         flagsML, flagsL2, xcd_ids, vflag);
}

// Round 17
// 976.152 us; speedup vs baseline: 1.0993x; 1.0993x over previous
//
#include <hip/hip_runtime.h>
#include <hip/hip_bf16.h>

#define BATCH 256
#define SEQ   250
#define HID   512
#define INDIM 5

#define NBLK  256
#define NCH   16   // independent batch chains
#define MB    16   // batch rows per chain/block
#define HB    32   // hidden cols per block per gate -> 16 members per chain
#define NMEM  16   // members per chain (HID/HB)

// member-major h buffers: slot (2) | chain (16) | member (16) | 1KB
//   member block: 16 rows (batch) x 32 cols (hidden) bf16 = 16 x 64B
// A-fragment for kb == member kb: lane(n16,q) reads kb*1024 + n16*64 + q*16
// -> ONE coalesced dwordx4 per member per wave. No LDS staging at all.
#define SLOT_BYTES (BATCH * HID * 2)   // 256KB per slot

typedef __attribute__((ext_vector_type(8))) short short8;
typedef __attribute__((ext_vector_type(4))) float f32x4;
typedef __attribute__((ext_vector_type(4))) unsigned int u32x4;

__device__ __forceinline__ float sigmoidf_fast(float x) {
  return 1.0f / (1.0f + __expf(-x));
}
__device__ __forceinline__ float tanhf_fast(float x) {
  return 2.0f / (1.0f + __expf(-2.0f * x)) - 1.0f;
}
__device__ __forceinline__ unsigned short f2bf_rne(float x) {
  union { float f; unsigned u; } v; v.f = x;
  unsigned r = v.u + 0x7fffu + ((v.u >> 16) & 1u);
  return (unsigned short)(r >> 16);
}
__device__ __forceinline__ float bf2f(unsigned short h) {
  union { unsigned u; float f; } v; v.u = ((unsigned)h) << 16;
  return v.f;
}

// R17 = R16 + the register-dependency fix. R16's NaN: af[] loads were
// separate volatile asms and the MFMA consumers are pure register ops, so
// the compiler could (and did) schedule v_mfma before the s_waitcnt drain
// -- asm loads aren't in its vmcnt hazard model. Fix: the drain asm takes
// all 16 af quads as "+v" read-write operands, so every MFMA depends on a
// value defined AFTER vmcnt(0); volatile asms are mutually ordered ->
// loads -> drain -> MFMA is forced. (R4-R15 were safe only because their
// consumers were LDS stores, which the "memory" clobber orders.)
#define AF_DRAIN(af) \
  asm volatile("s_waitcnt vmcnt(0)" \
               : "+v"(af[0]), "+v"(af[1]), "+v"(af[2]), "+v"(af[3]), \
                 "+v"(af[4]), "+v"(af[5]), "+v"(af[6]), "+v"(af[7]), \
                 "+v"(af[8]), "+v"(af[9]), "+v"(af[10]), "+v"(af[11]), \
                 "+v"(af[12]), "+v"(af[13]), "+v"(af[14]), "+v"(af[15]) \
               :: "memory")

__global__ __launch_bounds__(256, 1) void lstm_persist(
    const float* __restrict__ strokes, const float* __restrict__ W_ih,
    const float* __restrict__ W_hh, const float* __restrict__ b_ih,
    const float* __restrict__ b_hh, const float* __restrict__ W_out,
    const float* __restrict__ b_out, float* __restrict__ out,
    unsigned short* __restrict__ hbuf,   // 2 slots * 256KB, member-major
    int* __restrict__ flagsML,           // 16*16*16 ints, MALL copy (poison<0)
    int* __restrict__ flagsL2,           // 16*16*16 ints, L2 copy   (poison<0)
    int* __restrict__ xcd_ids,           // 256 ints (poison < 0)
    int* __restrict__ vflag)             // 16*16 ints verdicts (poison < 0)
{
  const int tid  = threadIdx.x;
  const int bid  = blockIdx.x;
  const int bt   = bid & 15;     // chain id (16 chains)
  const int ht   = bid >> 4;     // member 0..15
  const int wv   = tid >> 6;     // wave id = gate type 0..3 (i,f,g,o)
  const int lane = tid & 63;
  const int n16  = lane & 15;
  const int q    = lane >> 4;

  __shared__ float g_lds[4][MB][33];              // gates, padded
  __shared__ float wih_lds[4][HB][INDIM];
  __shared__ float bias_lds[4][HB];
  __shared__ unsigned short h_fin[NMEM * 576];    // final-proj staging only
  __shared__ int fast_s;

  // ---- publish my XCC id (device scope)
  unsigned xcc;
  asm volatile("s_getreg_b32 %0, hwreg(HW_REG_XCC_ID)" : "=s"(xcc));
  xcc &= 0xfu;
  if (tid == 0) {
    __hip_atomic_store(&xcd_ids[bid], (int)xcc, __ATOMIC_RELAXED,
                       __HIP_MEMORY_SCOPE_AGENT);
  }
  // ---- leader (ht==0 i.e. bid<16) computes chain verdict, BOUNDED poll
  if (bid < 16 && wv == 0) {
    int other = (int)xcc;
    if (lane < NMEM) {
      const int* xp = &xcd_ids[bid + 16 * lane];
      other = -1;
      for (int it = 0; it < 16384 && other < 0; ++it) {
        other = __hip_atomic_load(xp, __ATOMIC_RELAXED, __HIP_MEMORY_SCOPE_AGENT);
      }
    }
    unsigned long long ok = __ballot(other == (int)xcc);
    if (lane == 0) {
      __hip_atomic_store(&vflag[bid * 16], (ok == ~0ull) ? 2 : 1,
                         __ATOMIC_RELAXED, __HIP_MEMORY_SCOPE_AGENT);
    }
  }
  if (tid == 0) {
    int v;
    do {
      v = __hip_atomic_load(&vflag[bt * 16], __ATOMIC_RELAXED,
                            __HIP_MEMORY_SCOPE_AGENT);
    } while (v <= 0);
    fast_s = (v == 2) ? 1 : 0;
  }

  // ---- preload W_ih slice + combined biases into LDS (HB=32 per gate)
  if (tid < 128) {
    int g = tid >> 5, j = tid & 31;
    int r = g * HID + ht * HB + j;
    #pragma unroll
    for (int i = 0; i < INDIM; ++i) wih_lds[g][j][i] = W_ih[r * INDIM + i];
    bias_lds[g][j] = b_ih[r] + b_hh[r];
  }

  // ---- preload W_hh as bf16 MFMA B-fragments, 2 N-tiles per wave
  short8 wfrag[16][2];
  {
    #pragma unroll
    for (int kb = 0; kb < 16; ++kb) {
      #pragma unroll
      for (int nt = 0; nt < 2; ++nt) {
        const float* p = W_hh
            + (size_t)(wv * HID + ht * HB + nt * 16 + n16) * HID
            + kb * 32 + q * 8;
        short8 f;
        #pragma unroll
        for (int j = 0; j < 8; ++j) f[j] = (short)f2bf_rne(p[j]);
        wfrag[kb][nt] = f;
      }
    }
  }
  __syncthreads();
  const bool fast = fast_s != 0;

  // activation-phase mapping: thread -> (batch row am, hidden pair ajp)
  const int am  = tid >> 4;           // 0..15
  const int ajp = (tid & 15) * 2;     // 0,2,..,30
  const int ab  = bt * MB + am;       // global batch row
  // poll mapping: lane l watches (member l>>2, wave l&3)
  const int pfi = (bt * 16 + (lane >> 2)) * 16 + (lane & 3) * 4;
  // A-fragment per-lane offset within a member block
  const int aoff = n16 * 64 + q * 16;
  float c0 = 0.f, c1 = 0.f;

  for (int t = 0; t < SEQ; ++t) {
    char* hslotprev = reinterpret_cast<char*>(hbuf)
                    + (((t & 1) ^ 1) ? SLOT_BYTES : 0);
    char* hslotcur  = reinterpret_cast<char*>(hbuf)
                    + ((t & 1) ? SLOT_BYTES : 0);

    const float* sp = strokes + ((size_t)ab * SEQ + t) * INDIM;
    float s0 = sp[0], s1 = sp[1], s2 = sp[2], s3 = sp[3], s4 = sp[4];

    f32x4 acc[2][2] = {};   // [ntile][parity]
    if (t > 0) {
      // ---- poll: every lane one (member,wave) flag, fused dual-probe
      {
        const int* fpL = &flagsL2[pfi];
        const int* fpM = &flagsML[pfi];
        if (fast) {
          int v;
          do {
            int v1, v2;
            asm volatile("global_load_dword %0, %2, off sc0\n\t"
                         "global_load_dword %1, %3, off sc0 sc1\n\t"
                         "s_waitcnt vmcnt(0)"
                         : "=v"(v1), "=v"(v2)
                         : "v"(fpL), "v"(fpM)
                         : "memory");
            v = v1 > v2 ? v1 : v2;
          } while (v < t);
        } else {
          while (__hip_atomic_load(fpM, __ATOMIC_RELAXED,
                                   __HIP_MEMORY_SCOPE_AGENT) < t) { }
        }
      }
      // ---- direct L2 -> register A-fragments: 16 coalesced dwordx4
      const char* base = hslotprev + bt * 16384 + aoff;
      u32x4 af[16];
      if (fast) {
        #pragma unroll
        for (int kb = 0; kb < 16; ++kb)
          asm volatile("global_load_dwordx4 %0, %1, off sc0"
                       : "=v"(af[kb]) : "v"(base + kb * 1024) : "memory");
      } else {
        #pragma unroll
        for (int kb = 0; kb < 16; ++kb)
          asm volatile("global_load_dwordx4 %0, %1, off sc0 sc1"
                       : "=v"(af[kb]) : "v"(base + kb * 1024) : "memory");
      }
      AF_DRAIN(af);   // drain DEFINES af[0..15]: MFMA cannot precede vmcnt(0)
      #pragma unroll
      for (int kb = 0; kb < 16; ++kb) {
        const short8 a = *reinterpret_cast<const short8*>(&af[kb]);
        #pragma unroll
        for (int nt = 0; nt < 2; ++nt)
          acc[nt][kb & 1] = __builtin_amdgcn_mfma_f32_16x16x32_bf16(
              a, wfrag[kb][nt], acc[nt][kb & 1], 0, 0, 0);
      }
    }

    // C-layout per N-tile: col = nt*16 + (lane&15), row = q*4 + reg.
    // Anti-dependence vs previous step's act reads is enforced by the poll
    // (each wave published only after its act; we polled all waves >= t).
    #pragma unroll
    for (int nt = 0; nt < 2; ++nt) {
      #pragma unroll
      for (int r = 0; r < 4; ++r) {
        g_lds[wv][q * 4 + r][nt * 16 + n16] = acc[nt][0][r] + acc[nt][1][r];
      }
    }
    __syncthreads();   // the ONE barrier: gates visible to all waves

    // ---- act: 2 cells per thread (batch am, hidden ajp, ajp+1)
    float hv[2];
    #pragma unroll
    for (int e = 0; e < 2; ++e) {
      const int j = ajp + e;
      float pre[4];
      #pragma unroll
      for (int g = 0; g < 4; ++g) {
        pre[g] = bias_lds[g][j] + g_lds[g][am][j]
               + s0 * wih_lds[g][j][0] + s1 * wih_lds[g][j][1]
               + s2 * wih_lds[g][j][2] + s3 * wih_lds[g][j][3]
               + s4 * wih_lds[g][j][4];
      }
      float ig = sigmoidf_fast(pre[0]);
      float fg = sigmoidf_fast(pre[1]);
      float gg = tanhf_fast(pre[2]);
      float og = sigmoidf_fast(pre[3]);
      float& c = e ? c1 : c0;
      c = fg * c + ig * gg;
      hv[e] = og * tanhf_fast(c);
    }
    // h store: one dword (2 bf16) into member ht's 1KB block
    unsigned pack = (unsigned)f2bf_rne(hv[0]) | ((unsigned)f2bf_rne(hv[1]) << 16);
    unsigned* hp = reinterpret_cast<unsigned*>(
        hslotcur + bt * 16384 + ht * 1024 + am * 64 + ajp * 2);
    if (fast) {
      asm volatile("global_store_dword %0, %1, off sc0"
                   :: "v"(hp), "v"(pack) : "memory");
    } else {
      __hip_atomic_store(hp, pack, __ATOMIC_RELAXED, __HIP_MEMORY_SCOPE_AGENT);
    }

    // ---- per-wave publish: drain OWN wave's h stores, then flag
    asm volatile("s_waitcnt vmcnt(0)" ::: "memory");
    const int gen = t + 1;
    if (lane == 0) {
      const int fi = (bt * 16 + ht) * 16 + wv * 4;
      if (fast) {
        asm volatile("global_store_dword %0, %1, off sc0"
                     :: "v"(&flagsL2[fi]), "v"(gen) : "memory");
      }
      __hip_atomic_store(&flagsML[fi], gen, __ATOMIC_RELAXED,
                         __HIP_MEMORY_SCOPE_AGENT);   // MALL copy
    }
  }

  // ---- final projection: member ht==0 of each chain, 16 rows.
  if (ht == 0) {
    // wait for all members' final publish (lane -> (member,wave) as above)
    {
      const int* fpL = &flagsL2[pfi];
      const int* fpM = &flagsML[pfi];
      if (fast) {
        int v;
        do {
          int v1, v2;
          asm volatile("global_load_dword %0, %2, off sc0\n\t"
                       "global_load_dword %1, %3, off sc0 sc1\n\t"
                       "s_waitcnt vmcnt(0)"
                       : "=v"(v1), "=v"(v2)
                       : "v"(fpL), "v"(fpM)
                       : "memory");
          v = v1 > v2 ? v1 : v2;
        } while (v < SEQ);
      } else {
        while (__hip_atomic_load(fpM, __ATOMIC_RELAXED,
                                 __HIP_MEMORY_SCOPE_AGENT) < SEQ) { }
      }
    }
    // stage h(SEQ-1) for this chain into LDS (wave wv: members wv*4..wv*4+3)
    // (tmp -> LDS store consumers are memory ops: ordered by the drain's
    // "memory" clobber, so the plain drain is safe here)
    const char* base = reinterpret_cast<const char*>(hbuf)
                     + ((SEQ - 1) & 1) * SLOT_BYTES + bt * 16384
                     + (wv * 4) * 1024;
    u32x4 tmp[4];
    if (fast) {
      #pragma unroll
      for (int i = 0; i < 4; ++i)
        asm volatile("global_load_dwordx4 %0, %1, off sc0"
                     : "=v"(tmp[i])
                     : "v"(base + (size_t)(i * 64 + lane) * 16) : "memory");
    } else {
      #pragma unroll
      for (int i = 0; i < 4; ++i)
        asm volatile("global_load_dwordx4 %0, %1, off sc0 sc1"
                     : "=v"(tmp[i])
                     : "v"(base + (size_t)(i * 64 + lane) * 16) : "memory");
    }
    asm volatile("s_waitcnt vmcnt(0)" ::: "memory");
    #pragma unroll
    for (int i = 0; i < 4; ++i) {
      const int idx = i * 64 + lane;
      const int mm  = wv * 4 + (idx >> 6);
      const int c   = idx & 63;     // 16B chunk in member (4 per 64B row)
      *reinterpret_cast<u32x4*>(
          &h_fin[mm * 576 + (c >> 2) * 36 + (c & 3) * 8]) = tmp[i];
    }
    __syncthreads();
    if (tid < MB) {
      const int b = bt * MB + tid;
      float s = 0.f;
      for (int k = 0; k < HID; ++k) {
        s += bf2f(h_fin[(k >> 5) * 576 + tid * 36 + (k & 31)]) * W_out[k];
      }
      float raw = s + b_out[0];
      float lr = raw > 0.f ? raw : 0.1f * raw;
      out[b] = 1.0f / (1.0f + __expf(-lr));
    }
  }
}

extern "C" void kernel_launch(void* const* d_in, const int* in_sizes, int n_in,
                              void* d_out, int out_size, void* d_ws, size_t ws_size,
                              hipStream_t stream) {
  const float* strokes = (const float*)d_in[0];
  const float* W_ih    = (const float*)d_in[1];
  const float* W_hh    = (const float*)d_in[2];
  const float* b_ih    = (const float*)d_in[3];
  const float* b_hh    = (const float*)d_in[4];
  const float* W_out   = (const float*)d_in[5];
  const float* b_out   = (const float*)d_in[6];
  float* out = (float*)d_out;

  char* ws = (char*)d_ws;
  unsigned short* hbuf = (unsigned short*)ws;                 // 512 KB (2 slots)
  size_t off = (size_t)2 * SLOT_BYTES;
  int* flagsML = (int*)(ws + off);  off += 16384;             // 16 KB
  int* flagsL2 = (int*)(ws + off);  off += 16384;             // 16 KB
  int* xcd_ids = (int*)(ws + off);  off += 2048;              // 2 KB
  int* vflag   = (int*)(ws + off);                            // 1 KB

  lstm_persist<<<NBLK, 256, 0, stream>>>(strokes, W_ih, W_hh, b_ih, b_hh,
                                         W_out, b_out, out, hbuf,
                                         flagsML, flagsL2, xcd_ids, vflag);
}

// Round 18
// 973.327 us; speedup vs baseline: 1.1025x; 1.0029x over previous
//
#include <hip/hip_runtime.h>
#include <hip/hip_bf16.h>

#define BATCH 256
#define SEQ   250
#define HID   512
#define INDIM 5

#define NBLK  256
#define NCH   16   // independent batch chains
#define MB    16   // batch rows per chain/block
#define HB    32   // hidden cols per block per gate -> 16 members per chain
#define NMEM  16   // members per chain (HID/HB)

// member-major h buffers: slot (2) | chain (16) | member (16) | 1KB
//   member block: 16 rows (batch) x 32 cols (hidden) bf16 = 16 x 64B
// A-fragment for kb == member kb: lane(n16,q) reads kb*1024 + n16*64 + q*16
// -> ONE coalesced dwordx4 per member per wave. No LDS staging.
#define SLOT_BYTES (BATCH * HID * 2)   // 256KB per slot

typedef __attribute__((ext_vector_type(8))) short short8;
typedef __attribute__((ext_vector_type(4))) float f32x4;
typedef __attribute__((ext_vector_type(4))) unsigned int u32x4;

__device__ __forceinline__ float sigmoidf_fast(float x) {
  return 1.0f / (1.0f + __expf(-x));
}
__device__ __forceinline__ float tanhf_fast(float x) {
  return 2.0f / (1.0f + __expf(-2.0f * x)) - 1.0f;
}
__device__ __forceinline__ unsigned short f2bf_rne(float x) {
  union { float f; unsigned u; } v; v.f = x;
  unsigned r = v.u + 0x7fffu + ((v.u >> 16) & 1u);
  return (unsigned short)(r >> 16);
}
__device__ __forceinline__ float bf2f(unsigned short h) {
  union { unsigned u; float f; } v; v.u = ((unsigned)h) << 16;
  return v.f;
}

// R18 = R17 + per-MEMBER single flag. R17's regression vs R14 (976 vs 849)
// was poll width: every wave watched all 64 (member,wave) flags -> 256
// poller lanes/block, 4x the MALL probe traffic (R1/R2-class contention).
// Fix: LDS arrival counter -- each wave drains its own h stores then
// atomicAdds; the wave seeing old==4t+3 publishes ONE flag for the member
// (dual L2+MALL). Pollers: 16 lanes x 1 flag per wave = 64/block (R14
// level). old==4t+3 implies all 4 waves drained -> data complete.
// AF_DRAIN: drain asm defines af[0..15] ("+v") so MFMA cannot be scheduled
// before vmcnt(0) (R16's NaN bug, fixed in R17).
#define AF_DRAIN(af) \
  asm volatile("s_waitcnt vmcnt(0)" \
               : "+v"(af[0]), "+v"(af[1]), "+v"(af[2]), "+v"(af[3]), \
                 "+v"(af[4]), "+v"(af[5]), "+v"(af[6]), "+v"(af[7]), \
                 "+v"(af[8]), "+v"(af[9]), "+v"(af[10]), "+v"(af[11]), \
                 "+v"(af[12]), "+v"(af[13]), "+v"(af[14]), "+v"(af[15]) \
               :: "memory")

__global__ __launch_bounds__(256, 1) void lstm_persist(
    const float* __restrict__ strokes, const float* __restrict__ W_ih,
    const float* __restrict__ W_hh, const float* __restrict__ b_ih,
    const float* __restrict__ b_hh, const float* __restrict__ W_out,
    const float* __restrict__ b_out, float* __restrict__ out,
    unsigned short* __restrict__ hbuf,   // 2 slots * 256KB, member-major
    int* __restrict__ flagsML,           // 16*16*16 ints, MALL copy (poison<0)
    int* __restrict__ flagsL2,           // 16*16*16 ints, L2 copy   (poison<0)
    int* __restrict__ xcd_ids,           // 256 ints (poison < 0)
    int* __restrict__ vflag)             // 16*16 ints verdicts (poison < 0)
{
  const int tid  = threadIdx.x;
  const int bid  = blockIdx.x;
  const int bt   = bid & 15;     // chain id (16 chains)
  const int ht   = bid >> 4;     // member 0..15
  const int wv   = tid >> 6;     // wave id = gate type 0..3 (i,f,g,o)
  const int lane = tid & 63;
  const int n16  = lane & 15;
  const int q    = lane >> 4;

  __shared__ float g_lds[4][MB][33];              // gates, padded
  __shared__ float wih_lds[4][HB][INDIM];
  __shared__ float bias_lds[4][HB];
  __shared__ unsigned short h_fin[NMEM * 576];    // final-proj staging only
  __shared__ int fast_s;
  __shared__ int arrive_cnt;                      // per-step wave arrivals

  if (tid == 0) arrive_cnt = 0;

  // ---- publish my XCC id (device scope)
  unsigned xcc;
  asm volatile("s_getreg_b32 %0, hwreg(HW_REG_XCC_ID)" : "=s"(xcc));
  xcc &= 0xfu;
  if (tid == 0) {
    __hip_atomic_store(&xcd_ids[bid], (int)xcc, __ATOMIC_RELAXED,
                       __HIP_MEMORY_SCOPE_AGENT);
  }
  // ---- leader (ht==0 i.e. bid<16) computes chain verdict, BOUNDED poll
  if (bid < 16 && wv == 0) {
    int other = (int)xcc;
    if (lane < NMEM) {
      const int* xp = &xcd_ids[bid + 16 * lane];
      other = -1;
      for (int it = 0; it < 16384 && other < 0; ++it) {
        other = __hip_atomic_load(xp, __ATOMIC_RELAXED, __HIP_MEMORY_SCOPE_AGENT);
      }
    }
    unsigned long long ok = __ballot(other == (int)xcc);
    if (lane == 0) {
      __hip_atomic_store(&vflag[bid * 16], (ok == ~0ull) ? 2 : 1,
                         __ATOMIC_RELAXED, __HIP_MEMORY_SCOPE_AGENT);
    }
  }
  if (tid == 0) {
    int v;
    do {
      v = __hip_atomic_load(&vflag[bt * 16], __ATOMIC_RELAXED,
                            __HIP_MEMORY_SCOPE_AGENT);
    } while (v <= 0);
    fast_s = (v == 2) ? 1 : 0;
  }

  // ---- preload W_ih slice + combined biases into LDS (HB=32 per gate)
  if (tid < 128) {
    int g = tid >> 5, j = tid & 31;
    int r = g * HID + ht * HB + j;
    #pragma unroll
    for (int i = 0; i < INDIM; ++i) wih_lds[g][j][i] = W_ih[r * INDIM + i];
    bias_lds[g][j] = b_ih[r] + b_hh[r];
  }

  // ---- preload W_hh as bf16 MFMA B-fragments, 2 N-tiles per wave
  short8 wfrag[16][2];
  {
    #pragma unroll
    for (int kb = 0; kb < 16; ++kb) {
      #pragma unroll
      for (int nt = 0; nt < 2; ++nt) {
        const float* p = W_hh
            + (size_t)(wv * HID + ht * HB + nt * 16 + n16) * HID
            + kb * 32 + q * 8;
        short8 f;
        #pragma unroll
        for (int j = 0; j < 8; ++j) f[j] = (short)f2bf_rne(p[j]);
        wfrag[kb][nt] = f;
      }
    }
  }
  __syncthreads();
  const bool fast = fast_s != 0;

  // activation-phase mapping: thread -> (batch row am, hidden pair ajp)
  const int am  = tid >> 4;           // 0..15
  const int ajp = (tid & 15) * 2;     // 0,2,..,30
  const int ab  = bt * MB + am;       // global batch row
  // poll mapping: lane l (l<16) watches member l's single flag
  const int pfi = (bt * 16 + n16) * 16;
  // A-fragment per-lane offset within a member block
  const int aoff = n16 * 64 + q * 16;
  float c0 = 0.f, c1 = 0.f;

  for (int t = 0; t < SEQ; ++t) {
    char* hslotprev = reinterpret_cast<char*>(hbuf)
                    + (((t & 1) ^ 1) ? SLOT_BYTES : 0);
    char* hslotcur  = reinterpret_cast<char*>(hbuf)
                    + ((t & 1) ? SLOT_BYTES : 0);

    const float* sp = strokes + ((size_t)ab * SEQ + t) * INDIM;
    float s0 = sp[0], s1 = sp[1], s2 = sp[2], s3 = sp[3], s4 = sp[4];

    f32x4 acc[2][2] = {};   // [ntile][parity]
    if (t > 0) {
      // ---- poll: 16 lanes, one member-flag each, fused dual-probe
      if (lane < 16) {
        const int* fpL = &flagsL2[pfi];
        const int* fpM = &flagsML[pfi];
        if (fast) {
          int v;
          do {
            int v1, v2;
            asm volatile("global_load_dword %0, %2, off sc0\n\t"
                         "global_load_dword %1, %3, off sc0 sc1\n\t"
                         "s_waitcnt vmcnt(0)"
                         : "=v"(v1), "=v"(v2)
                         : "v"(fpL), "v"(fpM)
                         : "memory");
            v = v1 > v2 ? v1 : v2;
          } while (v < t);
        } else {
          while (__hip_atomic_load(fpM, __ATOMIC_RELAXED,
                                   __HIP_MEMORY_SCOPE_AGENT) < t) { }
        }
      }
      // ---- direct L2 -> register A-fragments: 16 coalesced dwordx4
      const char* base = hslotprev + bt * 16384 + aoff;
      u32x4 af[16];
      if (fast) {
        #pragma unroll
        for (int kb = 0; kb < 16; ++kb)
          asm volatile("global_load_dwordx4 %0, %1, off sc0"
                       : "=v"(af[kb]) : "v"(base + kb * 1024) : "memory");
      } else {
        #pragma unroll
        for (int kb = 0; kb < 16; ++kb)
          asm volatile("global_load_dwordx4 %0, %1, off sc0 sc1"
                       : "=v"(af[kb]) : "v"(base + kb * 1024) : "memory");
      }
      AF_DRAIN(af);   // drain DEFINES af[0..15]: MFMA cannot precede vmcnt(0)
      #pragma unroll
      for (int kb = 0; kb < 16; ++kb) {
        const short8 a = *reinterpret_cast<const short8*>(&af[kb]);
        #pragma unroll
        for (int nt = 0; nt < 2; ++nt)
          acc[nt][kb & 1] = __builtin_amdgcn_mfma_f32_16x16x32_bf16(
              a, wfrag[kb][nt], acc[nt][kb & 1], 0, 0, 0);
      }
    }

    // C-layout per N-tile: col = nt*16 + (lane&15), row = q*4 + reg.
    // Anti-dependence vs previous step's act reads is enforced by the poll
    // (member flag published only after all waves' act+drain of step t).
    #pragma unroll
    for (int nt = 0; nt < 2; ++nt) {
      #pragma unroll
      for (int r = 0; r < 4; ++r) {
        g_lds[wv][q * 4 + r][nt * 16 + n16] = acc[nt][0][r] + acc[nt][1][r];
      }
    }
    __syncthreads();   // the ONE barrier: gates visible to all waves

    // ---- act: 2 cells per thread (batch am, hidden ajp, ajp+1)
    float hv[2];
    #pragma unroll
    for (int e = 0; e < 2; ++e) {
      const int j = ajp + e;
      float pre[4];
      #pragma unroll
      for (int g = 0; g < 4; ++g) {
        pre[g] = bias_lds[g][j] + g_lds[g][am][j]
               + s0 * wih_lds[g][j][0] + s1 * wih_lds[g][j][1]
               + s2 * wih_lds[g][j][2] + s3 * wih_lds[g][j][3]
               + s4 * wih_lds[g][j][4];
      }
      float ig = sigmoidf_fast(pre[0]);
      float fg = sigmoidf_fast(pre[1]);
      float gg = tanhf_fast(pre[2]);
      float og = sigmoidf_fast(pre[3]);
      float& c = e ? c1 : c0;
      c = fg * c + ig * gg;
      hv[e] = og * tanhf_fast(c);
    }
    // h store: one dword (2 bf16) into member ht's 1KB block
    unsigned pack = (unsigned)f2bf_rne(hv[0]) | ((unsigned)f2bf_rne(hv[1]) << 16);
    unsigned* hp = reinterpret_cast<unsigned*>(
        hslotcur + bt * 16384 + ht * 1024 + am * 64 + ajp * 2);
    if (fast) {
      asm volatile("global_store_dword %0, %1, off sc0"
                   :: "v"(hp), "v"(pack) : "memory");
    } else {
      __hip_atomic_store(hp, pack, __ATOMIC_RELAXED, __HIP_MEMORY_SCOPE_AGENT);
    }

    // ---- per-member publish: each wave drains ITS OWN h stores, then
    // arrives on the LDS counter; the LAST wave (old==4t+3) publishes the
    // member's single flag. old==4t+3 implies all 4 waves drained.
    asm volatile("s_waitcnt vmcnt(0)" ::: "memory");
    if (lane == 0) {
      const int old = atomicAdd(&arrive_cnt, 1);
      if (old == 4 * t + 3) {
        const int gen = t + 1;
        const int fi = (bt * 16 + ht) * 16;
        if (fast) {
          asm volatile("global_store_dword %0, %1, off sc0"
                       :: "v"(&flagsL2[fi]), "v"(gen) : "memory");
        }
        __hip_atomic_store(&flagsML[fi], gen, __ATOMIC_RELAXED,
                           __HIP_MEMORY_SCOPE_AGENT);   // MALL copy
      }
    }
  }

  // ---- final projection: member ht==0 of each chain, 16 rows.
  if (ht == 0) {
    if (lane < 16) {
      const int* fpL = &flagsL2[pfi];
      const int* fpM = &flagsML[pfi];
      if (fast) {
        int v;
        do {
          int v1, v2;
          asm volatile("global_load_dword %0, %2, off sc0\n\t"
                       "global_load_dword %1, %3, off sc0 sc1\n\t"
                       "s_waitcnt vmcnt(0)"
                       : "=v"(v1), "=v"(v2)
                       : "v"(fpL), "v"(fpM)
                       : "memory");
          v = v1 > v2 ? v1 : v2;
        } while (v < SEQ);
      } else {
        while (__hip_atomic_load(fpM, __ATOMIC_RELAXED,
                                 __HIP_MEMORY_SCOPE_AGENT) < SEQ) { }
      }
    }
    // stage h(SEQ-1) for this chain into LDS (wave wv: members wv*4..wv*4+3)
    // (LDS-store consumers are memory ops: plain drain is safe here)
    const char* base = reinterpret_cast<const char*>(hbuf)
                     + ((SEQ - 1) & 1) * SLOT_BYTES + bt * 16384
                     + (wv * 4) * 1024;
    u32x4 tmp[4];
    if (fast) {
      #pragma unroll
      for (int i = 0; i < 4; ++i)
        asm volatile("global_load_dwordx4 %0, %1, off sc0"
                     : "=v"(tmp[i])
                     : "v"(base + (size_t)(i * 64 + lane) * 16) : "memory");
    } else {
      #pragma unroll
      for (int i = 0; i < 4; ++i)
        asm volatile("global_load_dwordx4 %0, %1, off sc0 sc1"
                     : "=v"(tmp[i])
                     : "v"(base + (size_t)(i * 64 + lane) * 16) : "memory");
    }
    asm volatile("s_waitcnt vmcnt(0)" ::: "memory");
    #pragma unroll
    for (int i = 0; i < 4; ++i) {
      const int idx = i * 64 + lane;
      const int mm  = wv * 4 + (idx >> 6);
      const int c   = idx & 63;     // 16B chunk in member (4 per 64B row)
      *reinterpret_cast<u32x4*>(
          &h_fin[mm * 576 + (c >> 2) * 36 + (c & 3) * 8]) = tmp[i];
    }
    __syncthreads();
    if (tid < MB) {
      const int b = bt * MB + tid;
      float s = 0.f;
      for (int k = 0; k < HID; ++k) {
        s += bf2f(h_fin[(k >> 5) * 576 + tid * 36 + (k & 31)]) * W_out[k];
      }
      float raw = s + b_out[0];
      float lr = raw > 0.f ? raw : 0.1f * raw;
      out[b] = 1.0f / (1.0f + __expf(-lr));
    }
  }
}

extern "C" void kernel_launch(void* const* d_in, const int* in_sizes, int n_in,
                              void* d_out, int out_size, void* d_ws, size_t ws_size,
                              hipStream_t stream) {
  const float* strokes = (const float*)d_in[0];
  const float* W_ih    = (const float*)d_in[1];
  const float* W_hh    = (const float*)d_in[2];
  const float* b_ih    = (const float*)d_in[3];
  const float* b_hh    = (const float*)d_in[4];
  const float* W_out   = (const float*)d_in[5];
  const float* b_out   = (const float*)d_in[6];
  float* out = (float*)d_out;

  char* ws = (char*)d_ws;
  unsigned short* hbuf = (unsigned short*)ws;                 // 512 KB (2 slots)
  size_t off = (size_t)2 * SLOT_BYTES;
  int* flagsML = (int*)(ws + off);  off += 16384;             // 16 KB
  int* flagsL2 = (int*)(ws + off);  off += 16384;             // 16 KB
  int* xcd_ids = (int*)(ws + off);  off += 2048;              // 2 KB
  int* vflag   = (int*)(ws + off);                            // 1 KB

  lstm_persist<<<NBLK, 256, 0, stream>>>(strokes, W_ih, W_hh, b_ih, b_hh,
                                         W_out, b_out, out, hbuf,
                                         flagsML, flagsL2, xcd_ids, vflag);
}